// Round 4
// baseline (3374.353 us; speedup 1.0000x reference)
//
#include <hip/hip_runtime.h>
#include <stdint.h>

typedef _Float16 f16x8 __attribute__((ext_vector_type(8)));
typedef _Float16 f16x4 __attribute__((ext_vector_type(4)));
typedef float    f32x4 __attribute__((ext_vector_type(4)));

#define T_LEN 512

union HF8 { unsigned int u[4]; f16x8 v; };

// ---------------------------------------------------------------------------
// async global->LDS (16B/lane). LDS dest = wave-uniform base + lane*16.
// GLOBAL SOURCE IS PER-LANE: caller must pass this lane's address.
// ---------------------------------------------------------------------------
__device__ __forceinline__ void gload_lds16(const void* gsrc, void* ldsdst) {
    auto g = (const __attribute__((address_space(1))) void*)(reinterpret_cast<uintptr_t>(gsrc));
    auto s = (__attribute__((address_space(3))) void*)(reinterpret_cast<uintptr_t>(ldsdst));
    __builtin_amdgcn_global_load_lds(g, s, 16, 0, 0);
}
__device__ __forceinline__ void wait_vm0() {
    asm volatile("s_waitcnt vmcnt(0)" ::: "memory");
    __builtin_amdgcn_sched_barrier(0);
}
__device__ __forceinline__ unsigned int pack_tag(float x, unsigned int tag) {
    union { _Float16 h; unsigned short s; } c; c.h = (_Float16)x;
    return ((unsigned int)c.s << 16) | tag;
}

// ---------------------------------------------------------------------------
// prep: f16 weights (Wci=[W_iz;W_in], Whc=[W_hz;W_hn]), bc=b_i+b_h,
// zero tagged hbuf (tag 0 = seed for step 0). Runs every launch (replays).
// ---------------------------------------------------------------------------
__global__ __launch_bounds__(256) void prep_misc(
    const float* __restrict__ W_iz, const float* __restrict__ W_in,
    const float* __restrict__ W_hz, const float* __restrict__ W_hn,
    const float* __restrict__ b_iz, const float* __restrict__ b_in,
    const float* __restrict__ b_hz, const float* __restrict__ b_hn,
    _Float16* __restrict__ Wci, _Float16* __restrict__ Whc,
    float* __restrict__ bc, unsigned int* __restrict__ hbuf32)
{
    const int tid = blockIdx.x * 256 + threadIdx.x;
    if (tid < 131072) {                      // 2 * 1024*512/8 weight vec units
        const bool is_h = tid >= 65536;
        const int u = tid & 65535;
        const int e = u * 8;
        const int row = e >> 9;
        const int k = e & 511;
        const float* s;
        if (!is_h) s = (row < 512) ? (W_iz + (size_t)row * 512 + k)
                                   : (W_in + (size_t)(row - 512) * 512 + k);
        else       s = (row < 512) ? (W_hz + (size_t)row * 512 + k)
                                   : (W_hn + (size_t)(row - 512) * 512 + k);
        f32x4 a = *(const f32x4*)s;
        f32x4 b = *(const f32x4*)(s + 4);
        f16x8 o;
        o[0] = (_Float16)a[0]; o[1] = (_Float16)a[1];
        o[2] = (_Float16)a[2]; o[3] = (_Float16)a[3];
        o[4] = (_Float16)b[0]; o[5] = (_Float16)b[1];
        o[6] = (_Float16)b[2]; o[7] = (_Float16)b[3];
        _Float16* d = is_h ? Whc : Wci;
        *(f16x8*)(d + e) = o;
    } else if (tid < 132096) {               // 1024 combined biases
        const int j2 = tid - 131072;
        bc[j2] = (j2 < 512) ? (b_iz[j2] + b_hz[j2]) : (b_in[j2 - 512] + b_hn[j2 - 512]);
    } else if (tid < 164864) {               // zero tagged hbuf: 131072 u32 / 4
        const int u = tid - 132096;
        typedef unsigned int u32x4v __attribute__((ext_vector_type(4)));
        u32x4v z = {0u, 0u, 0u, 0u};
        *(u32x4v*)(hbuf32 + (size_t)u * 4) = z;
    }
}

// ---------------------------------------------------------------------------
// Phase 1: input projections -> BLOCKED izin layout (f16, into d_out):
//   record (t, blk_s, gate) at byte ((t*128+blk_s)*2+gate)*1024 + lane*16
//   lane record 16B = [gate jt0 quad (4 f16), gate jt1 quad (4 f16)]
//   where scan WG blk_s=(b>>4)*16+w_s owns b-row b, j-cols w_s*32..+32.
// 128x128 tile, BK=32, 4 waves, f16 MFMA 16x16x32, mfma(W,seq).
// ---------------------------------------------------------------------------
__global__ __launch_bounds__(256) void gemm_proj(
    const float* __restrict__ A,      // seq [65536][512] f32 (row = t*128+b)
    const _Float16* __restrict__ Bw,  // Wci [1024][512] f16
    const float* __restrict__ bc,     // [1024] f32
    _Float16* Co)                     // blocked izin (= d_out as f16)
{
    __shared__ _Float16 As[128 * 40];   // padded stride 40 f16
    __shared__ _Float16 Bs[128 * 32];   // linear (global_load_lds target)

    const int mt = blockIdx.x;          // = t
    const int nt = blockIdx.y;          // 0..7 (0-3: z gate, 4-7: n gate)
    const int m0 = mt * 128, n0 = nt * 128;
    const int tid = threadIdx.x;
    const int w = tid >> 6, l = tid & 63;
    const int wr = w >> 1, wc = w & 1;
    const int lrow = l & 15, lk = l >> 4;

    f32x4 acc[4][4] = {};

    const int arow = tid >> 1;
    const int acol = (tid & 1) * 16;

    for (int kt = 0; kt < 16; ++kt) {
        const int k0 = kt * 32;
        if (kt) __syncthreads();
        const float* as = A + (size_t)(m0 + arow) * 512 + k0 + acol;
        f32x4 a0 = *(const f32x4*)as;
        f32x4 a1 = *(const f32x4*)(as + 4);
        f32x4 a2 = *(const f32x4*)(as + 8);
        f32x4 a3 = *(const f32x4*)(as + 12);
        f16x8 h0, h1;
#pragma unroll
        for (int e = 0; e < 4; ++e) {
            h0[e] = (_Float16)a0[e]; h0[4 + e] = (_Float16)a1[e];
            h1[e] = (_Float16)a2[e]; h1[4 + e] = (_Float16)a3[e];
        }
        *(f16x8*)&As[arow * 40 + acol] = h0;
        *(f16x8*)&As[arow * 40 + acol + 8] = h1;
#pragma unroll
        for (int i = 0; i < 2; ++i) {
            const int chunk = w * 2 + i;
            const _Float16* gsrc =
                Bw + (size_t)(n0 + chunk * 16 + (l >> 2)) * 512 + k0 + (l & 3) * 8;
            gload_lds16(gsrc, &Bs[chunk * 512]);
        }
        __syncthreads();
        f16x8 af[4], bf[4];
#pragma unroll
        for (int i = 0; i < 4; ++i) {
            af[i] = *(const f16x8*)&As[(wr * 64 + i * 16 + lrow) * 40 + lk * 8];
            bf[i] = *(const f16x8*)&Bs[(wc * 64 + i * 16 + lrow) * 32 + lk * 8];
        }
#pragma unroll
        for (int mi = 0; mi < 4; ++mi)
#pragma unroll
            for (int ni = 0; ni < 4; ++ni)
                acc[mi][ni] = __builtin_amdgcn_mfma_f32_16x16x32_f16(
                    bf[ni], af[mi], acc[mi][ni], 0, 0, 0);
    }
    // epilogue: bias + cvt f16 + blocked store
    const int gate = nt >> 2;
#pragma unroll
    for (int mi = 0; mi < 4; ++mi) {
#pragma unroll
        for (int p = 0; p < 2; ++p) {
            const int j2q0 = n0 + wc * 64 + p * 32 + 4 * lk;
            const f32x4 b0 = *(const f32x4*)&bc[j2q0];
            const f32x4 b1 = *(const f32x4*)&bc[j2q0 + 16];
            f16x8 o;
#pragma unroll
            for (int r = 0; r < 4; ++r) {
                o[r]     = (_Float16)(acc[mi][2 * p][r]     + b0[r]);
                o[4 + r] = (_Float16)(acc[mi][2 * p + 1][r] + b1[r]);
            }
            const int blk_s = (wr * 4 + mi) * 16 + (nt & 3) * 4 + wc * 2 + p;
            _Float16* dst = Co + ((((size_t)mt * 128 + blk_s) * 2 + gate) * 512) + l * 8;
            *(f16x8*)dst = o;
        }
    }
}

// ---------------------------------------------------------------------------
// Phase 2: persistent scan, flagless (version tags embedded in h data).
// 128 WGs x 1 wave. group g = blk>>4 owns batch rows [16g,16g+16);
// slot w = blk&15 owns hidden cols [32w,32w+32), both gates.
// h exchange: hbuf32[2][128][512] u32, each u32 = (f16 h << 16) | step_tag.
// Consumer loads its rows' u32s (relaxed agent atomics), checks ALL tags==t,
// retries until fresh. No flags, no fences, no cache flushes.
// izin: LDS ring (4 slots x 2KB), prefetch depth 2 via global_load_lds
// (PER-LANE source addr = record + l*16!); the single pre-publish vmcnt(0)
// orders izin reads before the tag publish that licenses other WGs to
// overwrite those izin bytes with H.
// Weights: 64KB LDS, lane i <-> slot i (conflict-free ds_read_b128).
// ---------------------------------------------------------------------------
__global__ __launch_bounds__(64, 1) void gru_scan(
    const _Float16* __restrict__ Whc,   // [1024][512] f16
    const char* izb,                    // d_out bytes: blocked izin (aliases Hout)
    float* Hout,                        // d_out as f32 [t][b][j]
    unsigned int* hbuf32)               // [2][128][512] tagged u32
{
    __shared__ _Float16 wlds[64 * 512];   // 64 subtiles x 1KB = 64KB
    __shared__ _Float16 izlds[4 * 1024];  // 4 slots x 2KB ring

    const int blk = blockIdx.x;
    const int g = blk >> 4;
    const int w = blk & 15;
    const int l = threadIdx.x;
    const int lrow = l & 15, lk = l >> 4;
    const int j0 = w * 32;
    const int b = g * 16 + lrow;
    const size_t lb = (size_t)l * 16;     // per-lane byte offset for DMA source

    // ---- stage weights into LDS: subtile (gate, jt, s), lane i -> slot i
    for (int gate = 0; gate < 2; ++gate)
        for (int jt = 0; jt < 2; ++jt)
#pragma unroll
            for (int s = 0; s < 16; ++s) {
                const int sub = (gate * 2 + jt) * 16 + s;
                const _Float16* gsrc = Whc +
                    (size_t)(gate * 512 + j0 + jt * 16 + lrow) * 512 + s * 32 + lk * 8;
                gload_lds16(gsrc, &wlds[sub * 512]);
            }
    // ---- prefetch izin slots 0,1 (per-lane source addresses!)
    {
        const char* s0 = izb + (size_t)blk * 2048;
        gload_lds16(s0 + lb,        &izlds[0]);
        gload_lds16(s0 + 1024 + lb, &izlds[512]);
        const char* s1 = izb + 262144 + (size_t)blk * 2048;
        gload_lds16(s1 + lb,        &izlds[1024]);
        gload_lds16(s1 + 1024 + lb, &izlds[1024 + 512]);
    }
    wait_vm0();

    float hm0[4] = {0.f, 0.f, 0.f, 0.f};
    float hm1[4] = {0.f, 0.f, 0.f, 0.f};

    for (int t = 0; t < T_LEN; ++t) {
        // ---- izin for this step from LDS ring
        const f16x8 zrec = *(const f16x8*)&izlds[(t & 3) * 1024 + l * 8];
        const f16x8 nrec = *(const f16x8*)&izlds[(t & 3) * 1024 + 512 + l * 8];

        // ---- tagged h_{t-1} read + freshness check (retry until all tags==t)
        const unsigned int tag = (unsigned int)t;
        const unsigned long long tp = (unsigned long long)tag * 0x0000000100000001ull;
        const unsigned int* hrd =
            hbuf32 + (size_t)((t + 1) & 1) * 65536 + (size_t)b * 512;
        unsigned long long hq[64];
        while (true) {
#pragma unroll
            for (int s = 0; s < 16; ++s) {
                const unsigned long long* p =
                    (const unsigned long long*)(hrd + s * 32 + lk * 8);
                hq[4 * s + 0] = __hip_atomic_load(p + 0, __ATOMIC_RELAXED, __HIP_MEMORY_SCOPE_AGENT);
                hq[4 * s + 1] = __hip_atomic_load(p + 1, __ATOMIC_RELAXED, __HIP_MEMORY_SCOPE_AGENT);
                hq[4 * s + 2] = __hip_atomic_load(p + 2, __ATOMIC_RELAXED, __HIP_MEMORY_SCOPE_AGENT);
                hq[4 * s + 3] = __hip_atomic_load(p + 3, __ATOMIC_RELAXED, __HIP_MEMORY_SCOPE_AGENT);
            }
            unsigned long long acc = 0;
#pragma unroll
            for (int i = 0; i < 64; ++i) acc |= (hq[i] ^ tp);
            if (__all((acc & 0x0000FFFF0000FFFFull) == 0)) break;
            __builtin_amdgcn_s_sleep(1);
        }

        // ---- unpack + MFMA: 4 tiles (z/n x jt0/jt1), K=512
        f32x4 az0 = {0.f,0.f,0.f,0.f}, az1 = az0, an0 = az0, an1 = az0;
#pragma unroll
        for (int s = 0; s < 16; ++s) {
            HF8 hf;
#pragma unroll
            for (int jj = 0; jj < 4; ++jj) {
                const unsigned long long q = hq[4 * s + jj];
                const unsigned int lo = (unsigned int)q;
                const unsigned int hi = (unsigned int)(q >> 32);
                hf.u[jj] = (lo >> 16) | (hi & 0xFFFF0000u);
            }
            const f16x8 wz0 = *(const f16x8*)&wlds[(0 * 16 + s) * 512 + l * 8];
            const f16x8 wz1 = *(const f16x8*)&wlds[(1 * 16 + s) * 512 + l * 8];
            const f16x8 wn0 = *(const f16x8*)&wlds[(2 * 16 + s) * 512 + l * 8];
            const f16x8 wn1 = *(const f16x8*)&wlds[(3 * 16 + s) * 512 + l * 8];
            az0 = __builtin_amdgcn_mfma_f32_16x16x32_f16(wz0, hf.v, az0, 0, 0, 0);
            az1 = __builtin_amdgcn_mfma_f32_16x16x32_f16(wz1, hf.v, az1, 0, 0, 0);
            an0 = __builtin_amdgcn_mfma_f32_16x16x32_f16(wn0, hf.v, an0, 0, 0, 0);
            an1 = __builtin_amdgcn_mfma_f32_16x16x32_f16(wn1, hf.v, an1, 0, 0, 0);
        }

        // ---- gates + state update (f32); pack tagged h and H rows
        typedef unsigned int u32x4v __attribute__((ext_vector_type(4)));
        u32x4v th0, th1;
        f32x4 Hv0, Hv1;
#pragma unroll
        for (int r = 0; r < 4; ++r) {
            float zpre = az0[r] + (float)zrec[r];
            float npre = an0[r] + (float)nrec[r];
            zpre = fminf(fmaxf(zpre, -30.f), 30.f);
            const float z = 1.f / (1.f + __expf(-zpre));
            npre = fminf(fmaxf(npre, -15.f), 15.f);
            const float e2 = __expf(2.f * npre);
            const float n = (e2 - 1.f) / (e2 + 1.f);
            hm0[r] = (1.f - z) * n + z * hm0[r];
            Hv0[r] = hm0[r];
            th0[r] = pack_tag(hm0[r], tag + 1);

            float zpre1 = az1[r] + (float)zrec[4 + r];
            float npre1 = an1[r] + (float)nrec[4 + r];
            zpre1 = fminf(fmaxf(zpre1, -30.f), 30.f);
            const float z1 = 1.f / (1.f + __expf(-zpre1));
            npre1 = fminf(fmaxf(npre1, -15.f), 15.f);
            const float e21 = __expf(2.f * npre1);
            const float n1 = (e21 - 1.f) / (e21 + 1.f);
            hm1[r] = (1.f - z1) * n1 + z1 * hm1[r];
            Hv1[r] = hm1[r];
            th1[r] = pack_tag(hm1[r], tag + 1);
        }

        // ---- pre-publish drain: retires izin DMA + previous H stores;
        //      REQUIRED before tag publish.
        wait_vm0();

        // ---- publish tagged h_t (relaxed agent atomics, u64 granules)
        {
            unsigned long long* hwb0 = (unsigned long long*)
                (hbuf32 + (size_t)(t & 1) * 65536 + (size_t)b * 512 + j0 + 4 * lk);
            unsigned long long* hwb1 = (unsigned long long*)
                (hbuf32 + (size_t)(t & 1) * 65536 + (size_t)b * 512 + j0 + 16 + 4 * lk);
            const unsigned long long q00 = ((unsigned long long)th0[1] << 32) | th0[0];
            const unsigned long long q01 = ((unsigned long long)th0[3] << 32) | th0[2];
            const unsigned long long q10 = ((unsigned long long)th1[1] << 32) | th1[0];
            const unsigned long long q11 = ((unsigned long long)th1[3] << 32) | th1[2];
            __hip_atomic_store(hwb0 + 0, q00, __ATOMIC_RELAXED, __HIP_MEMORY_SCOPE_AGENT);
            __hip_atomic_store(hwb0 + 1, q01, __ATOMIC_RELAXED, __HIP_MEMORY_SCOPE_AGENT);
            __hip_atomic_store(hwb1 + 0, q10, __ATOMIC_RELAXED, __HIP_MEMORY_SCOPE_AGENT);
            __hip_atomic_store(hwb1 + 1, q11, __ATOMIC_RELAXED, __HIP_MEMORY_SCOPE_AGENT);
        }

        // ---- H[t] plain full-line stores (128B/row across the wave)
        *(f32x4*)&Hout[(size_t)t * 65536 + (size_t)b * 512 + j0 + 4 * lk] = Hv0;
        *(f32x4*)&Hout[(size_t)t * 65536 + (size_t)b * 512 + j0 + 16 + 4 * lk] = Hv1;

        // ---- prefetch izin[t+2] into ring slot (t+2)&3 (per-lane source!)
        if (t + 2 < T_LEN) {
            const char* src = izb + (size_t)(t + 2) * 262144 + (size_t)blk * 2048;
            gload_lds16(src + lb,        &izlds[((t + 2) & 3) * 1024]);
            gload_lds16(src + 1024 + lb, &izlds[((t + 2) & 3) * 1024 + 512]);
        }
    }
}

// ---------------------------------------------------------------------------
extern "C" void kernel_launch(void* const* d_in, const int* in_sizes, int n_in,
                              void* d_out, int out_size, void* d_ws, size_t ws_size,
                              hipStream_t stream) {
    (void)in_sizes; (void)n_in; (void)out_size; (void)ws_size;
    const float* seq  = (const float*)d_in[0];
    const float* W_iz = (const float*)d_in[1];
    const float* b_iz = (const float*)d_in[2];
    const float* W_in = (const float*)d_in[3];
    const float* b_in = (const float*)d_in[4];
    const float* W_hz = (const float*)d_in[5];
    const float* b_hz = (const float*)d_in[6];
    const float* W_hn = (const float*)d_in[7];
    const float* b_hn = (const float*)d_in[8];

    char* ws = (char*)d_ws;                         // total use: ~2.6 MB
    _Float16*     Wci    = (_Float16*)(ws);         // 1,048,576 B
    _Float16*     Whc    = (_Float16*)(ws + 1048576);
    float*        bc     = (float*)   (ws + 2097152);
    unsigned int* hbuf32 = (unsigned int*)(ws + 2101248);  // 524,288 B tagged

    prep_misc<<<644, 256, 0, stream>>>(W_iz, W_in, W_hz, W_hn,
                                       b_iz, b_in, b_hz, b_hn,
                                       Wci, Whc, bc, hbuf32);
    gemm_proj<<<dim3(512, 8), 256, 0, stream>>>(seq, Wci, bc, (_Float16*)d_out);
    gru_scan<<<128, 64, 0, stream>>>(Whc, (const char*)d_out, (float*)d_out, hbuf32);
}

// Round 6
// 2402.199 us; speedup vs baseline: 1.4047x; 1.4047x over previous
//
#include <hip/hip_runtime.h>
#include <stdint.h>

typedef _Float16 f16x8 __attribute__((ext_vector_type(8)));
typedef _Float16 f16x4 __attribute__((ext_vector_type(4)));
typedef float    f32x4 __attribute__((ext_vector_type(4)));

#define T_LEN 512

union U64x2 { unsigned long long u[2]; f16x8 v; };
union PK4   { _Float16 h[4]; unsigned long long q; };

// ---------------------------------------------------------------------------
// async global->LDS (16B/lane). LDS dest = wave-uniform base + lane*16.
// GLOBAL SOURCE IS PER-LANE: caller must pass this lane's address.
// ---------------------------------------------------------------------------
__device__ __forceinline__ void gload_lds16(const void* gsrc, void* ldsdst) {
    auto g = (const __attribute__((address_space(1))) void*)(reinterpret_cast<uintptr_t>(gsrc));
    auto s = (__attribute__((address_space(3))) void*)(reinterpret_cast<uintptr_t>(ldsdst));
    __builtin_amdgcn_global_load_lds(g, s, 16, 0, 0);
}
__device__ __forceinline__ void wait_vm0() {
    asm volatile("s_waitcnt vmcnt(0)" ::: "memory");
    __builtin_amdgcn_sched_barrier(0);
}

// ---------------------------------------------------------------------------
// prep: f16 weights (Wci=[W_iz;W_in], Whc=[W_hz;W_hn]), bc=b_i+b_h,
// zero hbuf (h_0 = 0), zero flags. Must run every launch (graph replays).
// ---------------------------------------------------------------------------
__global__ __launch_bounds__(256) void prep_misc(
    const float* __restrict__ W_iz, const float* __restrict__ W_in,
    const float* __restrict__ W_hz, const float* __restrict__ W_hn,
    const float* __restrict__ b_iz, const float* __restrict__ b_in,
    const float* __restrict__ b_hz, const float* __restrict__ b_hn,
    _Float16* __restrict__ Wci, _Float16* __restrict__ Whc,
    float* __restrict__ bc, _Float16* __restrict__ hbuf, int* __restrict__ flags)
{
    const int tid = blockIdx.x * 256 + threadIdx.x;
    if (tid < 131072) {                      // 2 * 1024*512/8 weight vec units
        const bool is_h = tid >= 65536;
        const int u = tid & 65535;
        const int e = u * 8;
        const int row = e >> 9;
        const int k = e & 511;
        const float* s;
        if (!is_h) s = (row < 512) ? (W_iz + (size_t)row * 512 + k)
                                   : (W_in + (size_t)(row - 512) * 512 + k);
        else       s = (row < 512) ? (W_hz + (size_t)row * 512 + k)
                                   : (W_hn + (size_t)(row - 512) * 512 + k);
        f32x4 a = *(const f32x4*)s;
        f32x4 b = *(const f32x4*)(s + 4);
        f16x8 o;
        o[0] = (_Float16)a[0]; o[1] = (_Float16)a[1];
        o[2] = (_Float16)a[2]; o[3] = (_Float16)a[3];
        o[4] = (_Float16)b[0]; o[5] = (_Float16)b[1];
        o[6] = (_Float16)b[2]; o[7] = (_Float16)b[3];
        _Float16* d = is_h ? Whc : Wci;
        *(f16x8*)(d + e) = o;
    } else if (tid < 132096) {               // 1024 combined biases
        const int j2 = tid - 131072;
        bc[j2] = (j2 < 512) ? (b_iz[j2] + b_hz[j2]) : (b_in[j2 - 512] + b_hn[j2 - 512]);
    } else if (tid < 148480) {               // zero hbuf: 131072 f16 / 8
        const int u = tid - 132096;
        f16x8 z = { (_Float16)0, (_Float16)0, (_Float16)0, (_Float16)0,
                    (_Float16)0, (_Float16)0, (_Float16)0, (_Float16)0 };
        *(f16x8*)(hbuf + (size_t)u * 8) = z;
    } else if (tid < 148608) {               // 128 flags
        flags[tid - 148480] = 0;
    }
}

// ---------------------------------------------------------------------------
// Phase 1: input projections -> BLOCKED izin layout (f16, into d_out):
//   record (t, blk_s, gate) at byte ((t*128+blk_s)*2+gate)*1024 + lane*16
//   where scan WG blk_s=(b>>4)*16+w_s owns b-row b, j-cols w_s*32..+32.
// 128x128 tile, BK=32, 4 waves, f16 MFMA 16x16x32, mfma(W,seq).
// (UNCHANGED — verified correct in round 4.)
// ---------------------------------------------------------------------------
__global__ __launch_bounds__(256) void gemm_proj(
    const float* __restrict__ A,      // seq [65536][512] f32 (row = t*128+b)
    const _Float16* __restrict__ Bw,  // Wci [1024][512] f16
    const float* __restrict__ bc,     // [1024] f32
    _Float16* Co)                     // blocked izin (= d_out as f16)
{
    __shared__ _Float16 As[128 * 40];   // padded stride 40 f16
    __shared__ _Float16 Bs[128 * 32];   // linear (global_load_lds target)

    const int mt = blockIdx.x;          // = t
    const int nt = blockIdx.y;          // 0..7 (0-3: z gate, 4-7: n gate)
    const int m0 = mt * 128, n0 = nt * 128;
    const int tid = threadIdx.x;
    const int w = tid >> 6, l = tid & 63;
    const int wr = w >> 1, wc = w & 1;
    const int lrow = l & 15, lk = l >> 4;

    f32x4 acc[4][4] = {};

    const int arow = tid >> 1;
    const int acol = (tid & 1) * 16;

    for (int kt = 0; kt < 16; ++kt) {
        const int k0 = kt * 32;
        if (kt) __syncthreads();
        const float* as = A + (size_t)(m0 + arow) * 512 + k0 + acol;
        f32x4 a0 = *(const f32x4*)as;
        f32x4 a1 = *(const f32x4*)(as + 4);
        f32x4 a2 = *(const f32x4*)(as + 8);
        f32x4 a3 = *(const f32x4*)(as + 12);
        f16x8 h0, h1;
#pragma unroll
        for (int e = 0; e < 4; ++e) {
            h0[e] = (_Float16)a0[e]; h0[4 + e] = (_Float16)a1[e];
            h1[e] = (_Float16)a2[e]; h1[4 + e] = (_Float16)a3[e];
        }
        *(f16x8*)&As[arow * 40 + acol] = h0;
        *(f16x8*)&As[arow * 40 + acol + 8] = h1;
#pragma unroll
        for (int i = 0; i < 2; ++i) {
            const int chunk = w * 2 + i;
            const _Float16* gsrc =
                Bw + (size_t)(n0 + chunk * 16 + (l >> 2)) * 512 + k0 + (l & 3) * 8;
            gload_lds16(gsrc, &Bs[chunk * 512]);
        }
        __syncthreads();
        f16x8 af[4], bf[4];
#pragma unroll
        for (int i = 0; i < 4; ++i) {
            af[i] = *(const f16x8*)&As[(wr * 64 + i * 16 + lrow) * 40 + lk * 8];
            bf[i] = *(const f16x8*)&Bs[(wc * 64 + i * 16 + lrow) * 32 + lk * 8];
        }
#pragma unroll
        for (int mi = 0; mi < 4; ++mi)
#pragma unroll
            for (int ni = 0; ni < 4; ++ni)
                acc[mi][ni] = __builtin_amdgcn_mfma_f32_16x16x32_f16(
                    bf[ni], af[mi], acc[mi][ni], 0, 0, 0);
    }
    // epilogue: bias + cvt f16 + blocked store
    const int gate = nt >> 2;
#pragma unroll
    for (int mi = 0; mi < 4; ++mi) {
#pragma unroll
        for (int p = 0; p < 2; ++p) {
            const int j2q0 = n0 + wc * 64 + p * 32 + 4 * lk;
            const f32x4 b0 = *(const f32x4*)&bc[j2q0];
            const f32x4 b1 = *(const f32x4*)&bc[j2q0 + 16];
            f16x8 o;
#pragma unroll
            for (int r = 0; r < 4; ++r) {
                o[r]     = (_Float16)(acc[mi][2 * p][r]     + b0[r]);
                o[4 + r] = (_Float16)(acc[mi][2 * p + 1][r] + b1[r]);
            }
            const int blk_s = (wr * 4 + mi) * 16 + (nt & 3) * 4 + wc * 2 + p;
            _Float16* dst = Co + ((((size_t)mt * 128 + blk_s) * 2 + gate) * 512) + l * 8;
            *(f16x8*)dst = o;
        }
    }
}

// ---------------------------------------------------------------------------
// Phase 2: persistent scan. Flag barrier (64B poll) + untagged f16 h exchange.
// 128 WGs x 1 wave. group g = blk>>4 owns batch rows [16g,16g+16);
// slot w = blk&15 owns hidden cols [32w,32w+32), both gates.
// Per step: poll 16 flags -> bulk h read ONCE (relaxed agent u64 atomics,
// 16KB/WG) -> 64 MFMA -> gates -> publish h (2 u64 atomics) -> vmcnt(0) ->
// flag=t+2 -> H stores + izin DMA (off the critical path; their retirement
// is covered by the NEXT step's pre-flag vmcnt(0)).
// Weights: 64KB LDS. izin: 4-slot LDS ring via global_load_lds (per-lane src).
// ---------------------------------------------------------------------------
__global__ __launch_bounds__(64, 1) void gru_scan(
    const _Float16* __restrict__ Whc,   // [1024][512] f16
    const char* izb,                    // d_out bytes: blocked izin (aliases Hout)
    float* Hout,                        // d_out as f32 [t][b][j]
    _Float16* hbuf,                     // [2][128][512] f16
    int* flags)                         // [8][16]
{
    __shared__ _Float16 wlds[64 * 512];   // 64 subtiles x 1KB = 64KB
    __shared__ _Float16 izlds[4 * 1024];  // 4 slots x 2KB ring

    const int blk = blockIdx.x;
    const int g = blk >> 4;
    const int w = blk & 15;
    const int l = threadIdx.x;
    const int lrow = l & 15, lk = l >> 4;
    const int j0 = w * 32;
    const int b = g * 16 + lrow;
    const size_t lb = (size_t)l * 16;     // per-lane byte offset for DMA source
    const int fi = g * 16 + (l & 15);     // each flag polled by 4 lanes
    const int myflag = g * 16 + w;

    // ---- stage weights into LDS: subtile (gate, jt, s), lane i -> slot i
    for (int gate = 0; gate < 2; ++gate)
        for (int jt = 0; jt < 2; ++jt)
#pragma unroll
            for (int s = 0; s < 16; ++s) {
                const int sub = (gate * 2 + jt) * 16 + s;
                const _Float16* gsrc = Whc +
                    (size_t)(gate * 512 + j0 + jt * 16 + lrow) * 512 + s * 32 + lk * 8;
                gload_lds16(gsrc, &wlds[sub * 512]);
            }
    // ---- prefetch izin slots 0,1 (per-lane source addresses!)
    {
        const char* s0 = izb + (size_t)blk * 2048;
        gload_lds16(s0 + lb,        &izlds[0]);
        gload_lds16(s0 + 1024 + lb, &izlds[512]);
        const char* s1 = izb + 262144 + (size_t)blk * 2048;
        gload_lds16(s1 + lb,        &izlds[1024]);
        gload_lds16(s1 + 1024 + lb, &izlds[1536]);
    }
    wait_vm0();
    if (l == 0)
        __hip_atomic_store(&flags[myflag], 1, __ATOMIC_RELAXED, __HIP_MEMORY_SCOPE_AGENT);

    float hm0[4] = {0.f, 0.f, 0.f, 0.f};
    float hm1[4] = {0.f, 0.f, 0.f, 0.f};

    for (int t = 0; t < T_LEN; ++t) {
        // ---- group barrier: all 16 WGs of group g at phase >= t+1
        const int target = t + 1;
        while (true) {
            int v = __hip_atomic_load(&flags[fi], __ATOMIC_RELAXED, __HIP_MEMORY_SCOPE_AGENT);
            if (__all(v >= target)) break;     // no sleep: load latency = backoff
        }
        asm volatile("" ::: "memory");

        // ---- bulk h_t read, ONCE (relaxed agent u64 atomics; 16B/lane/slice)
        const unsigned long long* hr = (const unsigned long long*)
            (hbuf + (size_t)((t + 1) & 1) * 65536 + (size_t)b * 512);
        U64x2 hh[16];
#pragma unroll
        for (int s = 0; s < 16; ++s) {
            hh[s].u[0] = __hip_atomic_load(hr + s * 8 + lk * 2,     __ATOMIC_RELAXED, __HIP_MEMORY_SCOPE_AGENT);
            hh[s].u[1] = __hip_atomic_load(hr + s * 8 + lk * 2 + 1, __ATOMIC_RELAXED, __HIP_MEMORY_SCOPE_AGENT);
        }

        // ---- izin for this step from LDS ring
        const f16x8 zrec = *(const f16x8*)&izlds[(t & 3) * 1024 + l * 8];
        const f16x8 nrec = *(const f16x8*)&izlds[(t & 3) * 1024 + 512 + l * 8];

        // ---- MFMA: 4 tiles (z/n x jt0/jt1), K=512
        f32x4 az0 = {0.f,0.f,0.f,0.f}, az1 = az0, an0 = az0, an1 = az0;
#pragma unroll
        for (int s = 0; s < 16; ++s) {
            const f16x8 hv = hh[s].v;
            const f16x8 wz0 = *(const f16x8*)&wlds[(0 * 16 + s) * 512 + l * 8];
            const f16x8 wz1 = *(const f16x8*)&wlds[(1 * 16 + s) * 512 + l * 8];
            const f16x8 wn0 = *(const f16x8*)&wlds[(2 * 16 + s) * 512 + l * 8];
            const f16x8 wn1 = *(const f16x8*)&wlds[(3 * 16 + s) * 512 + l * 8];
            az0 = __builtin_amdgcn_mfma_f32_16x16x32_f16(wz0, hv, az0, 0, 0, 0);
            az1 = __builtin_amdgcn_mfma_f32_16x16x32_f16(wz1, hv, az1, 0, 0, 0);
            an0 = __builtin_amdgcn_mfma_f32_16x16x32_f16(wn0, hv, an0, 0, 0, 0);
            an1 = __builtin_amdgcn_mfma_f32_16x16x32_f16(wn1, hv, an1, 0, 0, 0);
        }

        // ---- gates + state update (f32)
        PK4 p0, p1;
        f32x4 Hv0, Hv1;
#pragma unroll
        for (int r = 0; r < 4; ++r) {
            float zpre = az0[r] + (float)zrec[r];
            float npre = an0[r] + (float)nrec[r];
            zpre = fminf(fmaxf(zpre, -30.f), 30.f);
            const float z = 1.f / (1.f + __expf(-zpre));
            npre = fminf(fmaxf(npre, -15.f), 15.f);
            const float e2 = __expf(2.f * npre);
            const float n = (e2 - 1.f) / (e2 + 1.f);
            hm0[r] = (1.f - z) * n + z * hm0[r];
            Hv0[r] = hm0[r];
            p0.h[r] = (_Float16)hm0[r];

            float zpre1 = az1[r] + (float)zrec[4 + r];
            float npre1 = an1[r] + (float)nrec[4 + r];
            zpre1 = fminf(fmaxf(zpre1, -30.f), 30.f);
            const float z1 = 1.f / (1.f + __expf(-zpre1));
            npre1 = fminf(fmaxf(npre1, -15.f), 15.f);
            const float e21 = __expf(2.f * npre1);
            const float n1 = (e21 - 1.f) / (e21 + 1.f);
            hm1[r] = (1.f - z1) * n1 + z1 * hm1[r];
            Hv1[r] = hm1[r];
            p1.h[r] = (_Float16)hm1[r];
        }

        // ---- publish h_{t+1} (2 u64 write-through atomics), drain, flag
        //      p0 -> f16 offset j0+4lk (hw); p1 -> j0+16+4lk = hw + 4 u64 (32B)
        {
            unsigned long long* hw = (unsigned long long*)
                (hbuf + (size_t)(t & 1) * 65536 + (size_t)b * 512 + j0 + 4 * lk);
            __hip_atomic_store(hw,     p0.q, __ATOMIC_RELAXED, __HIP_MEMORY_SCOPE_AGENT);
            __hip_atomic_store(hw + 4, p1.q, __ATOMIC_RELAXED, __HIP_MEMORY_SCOPE_AGENT);
        }
        wait_vm0();   // drains: h publish + prev-step H stores + prev-step izin DMA
        if (l == 0)
            __hip_atomic_store(&flags[myflag], t + 2, __ATOMIC_RELAXED, __HIP_MEMORY_SCOPE_AGENT);

        // ---- H[t] stores (plain, full 128B lines; off critical path)
        *(f32x4*)&Hout[(size_t)t * 65536 + (size_t)b * 512 + j0 + 4 * lk] = Hv0;
        *(f32x4*)&Hout[(size_t)t * 65536 + (size_t)b * 512 + j0 + 16 + 4 * lk] = Hv1;

        // ---- prefetch izin[t+2] into ring slot (t+2)&3 (per-lane source!)
        if (t + 2 < T_LEN) {
            const char* src = izb + (size_t)(t + 2) * 262144 + (size_t)blk * 2048;
            gload_lds16(src + lb,        &izlds[((t + 2) & 3) * 1024]);
            gload_lds16(src + 1024 + lb, &izlds[((t + 2) & 3) * 1024 + 512]);
        }
    }
}

// ---------------------------------------------------------------------------
extern "C" void kernel_launch(void* const* d_in, const int* in_sizes, int n_in,
                              void* d_out, int out_size, void* d_ws, size_t ws_size,
                              hipStream_t stream) {
    (void)in_sizes; (void)n_in; (void)out_size; (void)ws_size;
    const float* seq  = (const float*)d_in[0];
    const float* W_iz = (const float*)d_in[1];
    const float* b_iz = (const float*)d_in[2];
    const float* W_in = (const float*)d_in[3];
    const float* b_in = (const float*)d_in[4];
    const float* W_hz = (const float*)d_in[5];
    const float* b_hz = (const float*)d_in[6];
    const float* W_hn = (const float*)d_in[7];
    const float* b_hn = (const float*)d_in[8];

    char* ws = (char*)d_ws;                         // total use: ~2.4 MB
    _Float16* Wci   = (_Float16*)(ws);              // 1,048,576 B
    _Float16* Whc   = (_Float16*)(ws + 1048576);    // 1,048,576 B
    float*    bc    = (float*)   (ws + 2097152);    //     4,096 B
    _Float16* hbuf  = (_Float16*)(ws + 2101248);    //   262,144 B
    int*      flags = (int*)     (ws + 2363392);    //       512 B

    prep_misc<<<581, 256, 0, stream>>>(W_iz, W_in, W_hz, W_hn,
                                       b_iz, b_in, b_hz, b_hn,
                                       Wci, Whc, bc, hbuf, flags);
    gemm_proj<<<dim3(512, 8), 256, 0, stream>>>(seq, Wci, bc, (_Float16*)d_out);
    gru_scan<<<128, 64, 0, stream>>>(Whc, (const char*)d_out, (float*)d_out,
                                     hbuf, flags);
}